// Round 10
// baseline (477.470 us; speedup 1.0000x reference)
//
#include <hip/hip_runtime.h>
#include <math.h>

#define N_NODES 128000
#define B_G 256
#define NPG 500
#define F_IN 128
#define D_LAT 32
#define K_TOP 30
#define L_LAYERS 3
#define E_EDGES 2048000

#define BSH 7                      // bucket = dst >> 7
#define NB (N_NODES >> BSH)        // 1000 buckets x 128 nodes
#define CHUNK 8192
#define CBLOCKS (E_EDGES / CHUNK)  // 250

// ---------------------------------------------------------------------------
// Fold the concat weights once: We = Wa0+Wa2, Wn = Wa1+Wa2 (per layer).
// ---------------------------------------------------------------------------
__global__ __launch_bounds__(256) void k_foldw(
    const float* __restrict__ W1a, float* __restrict__ wfold)
{
    const int l = blockIdx.x, t = threadIdx.x;
    const float* base = W1a + (size_t)l * 3 * D_LAT * D_LAT;
    float* o = wfold + (size_t)l * 2 * D_LAT * D_LAT;
    for (int i = t; i < D_LAT * D_LAT; i += 256) {
        const float wc = base[2 * D_LAT * D_LAT + i];
        o[i] = base[i] + wc;                                  // We
        o[D_LAT * D_LAT + i] = base[D_LAT * D_LAT + i] + wc;  // Wn
    }
}

// ---------------------------------------------------------------------------
// Kernel 1: ego = relu(X @ w0a + b0a) @ w0b + b0b ;  out = alpha[0] * ego
// Thread = row, scalar-path weights (wave-uniform addresses). Unchanged.
// ---------------------------------------------------------------------------
__global__ __launch_bounds__(256) void k_mlp0(
    const float* __restrict__ X, const float* __restrict__ w0a,
    const float* __restrict__ b0a, const float* __restrict__ w0b,
    const float* __restrict__ b0b, const float* __restrict__ alpha,
    float* __restrict__ ego, float* __restrict__ outb)
{
    const size_t row = (size_t)blockIdx.x * 256 + threadIdx.x;
    const float4* xp = (const float4*)(X + row * F_IN);
    const float a0 = alpha[0];

    float acc[D_LAT];
    #pragma unroll
    for (int j = 0; j < D_LAT; ++j) acc[j] = b0a[j];

    #pragma unroll 1
    for (int c = 0; c < F_IN / 16; ++c) {
        const float4 x0 = xp[c * 4 + 0], x1 = xp[c * 4 + 1];
        const float4 x2 = xp[c * 4 + 2], x3 = xp[c * 4 + 3];
        const float xs[16] = {x0.x, x0.y, x0.z, x0.w, x1.x, x1.y, x1.z, x1.w,
                              x2.x, x2.y, x2.z, x2.w, x3.x, x3.y, x3.z, x3.w};
        #pragma unroll
        for (int ff = 0; ff < 16; ++ff) {
            const float xf = xs[ff];
            const float* wr = w0a + (c * 16 + ff) * D_LAT;   // uniform addr
            #pragma unroll
            for (int j = 0; j < D_LAT; ++j)
                acc[j] = fmaf(xf, wr[j], acc[j]);
        }
    }

    #pragma unroll
    for (int j = 0; j < D_LAT; ++j) acc[j] = fmaxf(acc[j], 0.f);

    float acc2[D_LAT];
    #pragma unroll
    for (int j = 0; j < D_LAT; ++j) acc2[j] = b0b[j];
    #pragma unroll 1
    for (int c = 0; c < D_LAT / 8; ++c) {
        #pragma unroll
        for (int kk = 0; kk < 8; ++kk) {
            const float h = acc[c * 8 + kk];
            const float* wr = w0b + (c * 8 + kk) * D_LAT;    // uniform addr
            #pragma unroll
            for (int j = 0; j < D_LAT; ++j)
                acc2[j] = fmaf(h, wr[j], acc2[j]);
        }
    }

    float4* eo = (float4*)(ego + row * D_LAT);
    float4* oo = (float4*)(outb + row * D_LAT);
    #pragma unroll
    for (int q = 0; q < D_LAT / 4; ++q) {
        eo[q] = make_float4(acc2[q*4], acc2[q*4+1], acc2[q*4+2], acc2[q*4+3]);
        oo[q] = make_float4(a0*acc2[q*4], a0*acc2[q*4+1],
                            a0*acc2[q*4+2], a0*acc2[q*4+3]);
    }
}

// ---------------------------------------------------------------------------
// Radix CSR build
// ---------------------------------------------------------------------------
__global__ __launch_bounds__(256) void k_bcount(
    const int* __restrict__ edst, int* __restrict__ ghist)
{
    __shared__ int cnt[NB];
    const int t = threadIdx.x;
    for (int i = t; i < NB; i += 256) cnt[i] = 0;
    __syncthreads();
    const int ebase = blockIdx.x * CHUNK;
    for (int i = 0; i < CHUNK / 256; ++i)
        atomicAdd(&cnt[edst[ebase + i * 256 + t] >> BSH], 1);
    __syncthreads();
    for (int i = t; i < NB; i += 256)
        if (cnt[i]) atomicAdd(&ghist[i], cnt[i]);
}

__global__ __launch_bounds__(1024) void k_bscan(
    const int* __restrict__ ghist, int* __restrict__ gbase,
    int* __restrict__ gcursor)
{
    __shared__ int buf[2][1024];
    const int t = threadIdx.x;
    const int v = (t < NB) ? ghist[t] : 0;
    buf[0][t] = v;
    __syncthreads();
    int cur = 0;
    for (int o = 1; o < 1024; o <<= 1) {
        int x = buf[cur][t];
        if (t >= o) x += buf[cur][t - o];
        buf[cur ^ 1][t] = x;
        cur ^= 1;
        __syncthreads();
    }
    if (t < NB) { const int e = buf[cur][t] - v; gbase[t] = e; gcursor[t] = e; }
    if (t == 0) gbase[NB] = E_EDGES;
}

__global__ __launch_bounds__(256) void k_bscatter(
    const int* __restrict__ esrc, const int* __restrict__ edst,
    int* __restrict__ gcursor, int* __restrict__ packed)
{
    __shared__ int cnt[NB];
    __shared__ int sbase[NB];
    const int t = threadIdx.x;
    for (int i = t; i < NB; i += 256) cnt[i] = 0;
    __syncthreads();
    const int ebase = blockIdx.x * CHUNK;
    for (int i = 0; i < CHUNK / 256; ++i)
        atomicAdd(&cnt[edst[ebase + i * 256 + t] >> BSH], 1);
    __syncthreads();
    for (int i = t; i < NB; i += 256) {
        const int c = cnt[i];
        sbase[i] = c ? atomicAdd(&gcursor[i], c) : 0;
        cnt[i] = 0;
    }
    __syncthreads();
    for (int i = 0; i < CHUNK / 256; ++i) {
        const int e = ebase + i * 256 + t;
        const int d = edst[e], s = esrc[e];
        const int b = d >> BSH;
        const int r = atomicAdd(&cnt[b], 1);
        packed[sbase[b] + r] = (s << BSH) | (d & ((1 << BSH) - 1));
    }
}

// Per-bucket CSR finalize + NEW: per-node insertion sort by src id.
// Sorted neighbor lists turn the per-layer gather into a coordinated
// ascending sweep over the ego table -> small instantaneous working set
// -> L2-resident gathers (locality theory, this round's experiment).
__global__ __launch_bounds__(256) void k_bcsr(
    const int* __restrict__ gbase, const int* __restrict__ packed,
    int* __restrict__ off, int* __restrict__ srcidx)
{
    __shared__ int cnt[128];
    __shared__ int scn[128];
    __shared__ int sbuf[4096];
    const int b = blockIdx.x, t = threadIdx.x;
    const int s0 = gbase[b], s1 = gbase[b + 1], m = s1 - s0;

    if (t < 128) cnt[t] = 0;
    __syncthreads();
    for (int i = t; i < m; i += 256)
        atomicAdd(&cnt[packed[s0 + i] & 127], 1);
    __syncthreads();
    if (t == 0) {
        int a = 0;
        for (int k = 0; k < 128; ++k) { scn[k] = a; a += cnt[k]; }
    }
    __syncthreads();
    if (t < 128) { off[(b << BSH) + t] = s0 + scn[t]; cnt[t] = 0; }
    if (b == 0 && t == 0) off[N_NODES] = E_EDGES;
    __syncthreads();
    for (int i = t; i < m; i += 256) {
        const int p = packed[s0 + i];
        const int dl = p & 127;
        const int r = atomicAdd(&cnt[dl], 1);
        sbuf[scn[dl] + r] = p >> BSH;
    }
    __syncthreads();
    // insertion-sort each node's segment (avg 16 elems) ascending by src
    if (t < 128) {
        const int seg = scn[t], c = cnt[t];
        for (int a = 1; a < c; ++a) {
            const int v = sbuf[seg + a];
            int p = a - 1;
            while (p >= 0 && sbuf[seg + p] > v) {
                sbuf[seg + p + 1] = sbuf[seg + p];
                --p;
            }
            sbuf[seg + p + 1] = v;
        }
    }
    __syncthreads();
    for (int i = t; i < m; i += 256) srcidx[s0 + i] = sbuf[i];
}

// ---------------------------------------------------------------------------
// Fused layer (round-7 proven version, verbatim): thread = node, register
// gather of full 128-B rows, scalar-path weights, no LDS.
// ---------------------------------------------------------------------------
__global__ __launch_bounds__(256) void k_layer(
    const float* __restrict__ in, const int* __restrict__ off,
    const int* __restrict__ srcidx, const float* __restrict__ wfold_l,
    const float* __restrict__ W1b_l, const float* __restrict__ B1a_l,
    const float* __restrict__ B1b_l, const float* __restrict__ alpha,
    const int l, float* __restrict__ out, float* __restrict__ outb)
{
    const size_t n = (size_t)blockIdx.x * 256 + threadIdx.x;
    const int s0 = off[n], s1 = off[n + 1];
    const float al = alpha[l + 1];

    // register gather: neig = sum of neighbor rows (ascending src order)
    float4 ng4[D_LAT / 4];
    #pragma unroll
    for (int q = 0; q < D_LAT / 4; ++q) ng4[q] = make_float4(0.f, 0.f, 0.f, 0.f);
    int s = (s0 < s1) ? srcidx[s0] : 0;
    for (int i = s0; i < s1; ++i) {
        const int snext = (i + 1 < s1) ? srcidx[i + 1] : 0;
        const float4* vp = (const float4*)(in + (size_t)s * D_LAT);
        #pragma unroll
        for (int q = 0; q < D_LAT / 4; ++q) {
            const float4 v = vp[q];
            ng4[q].x += v.x; ng4[q].y += v.y; ng4[q].z += v.z; ng4[q].w += v.w;
        }
        s = snext;
    }
    float ngs[D_LAT];
    #pragma unroll
    for (int q = 0; q < D_LAT / 4; ++q) {
        ngs[q*4] = ng4[q].x; ngs[q*4+1] = ng4[q].y;
        ngs[q*4+2] = ng4[q].z; ngs[q*4+3] = ng4[q].w;
    }

    // own row
    float eg[D_LAT];
    {
        const float4* ep = (const float4*)(in + n * D_LAT);
        #pragma unroll
        for (int q = 0; q < D_LAT / 4; ++q) {
            const float4 v = ep[q];
            eg[q*4] = v.x; eg[q*4+1] = v.y; eg[q*4+2] = v.z; eg[q*4+3] = v.w;
        }
    }

    // stage 1: ego @ We + neig @ Wn + B1a (scalar-path weights)
    float acc[D_LAT];
    #pragma unroll
    for (int j = 0; j < D_LAT; ++j) acc[j] = B1a_l[j];
    #pragma unroll 1
    for (int c = 0; c < D_LAT / 8; ++c) {
        #pragma unroll
        for (int kk = 0; kk < 8; ++kk) {
            const int k = c * 8 + kk;
            const float fe = eg[k], fn = ngs[k];
            const float* we = wfold_l + k * D_LAT;                    // uniform
            const float* wn = wfold_l + D_LAT * D_LAT + k * D_LAT;    // uniform
            #pragma unroll
            for (int j = 0; j < D_LAT; ++j)
                acc[j] = fmaf(fe, we[j], fmaf(fn, wn[j], acc[j]));
        }
    }
    #pragma unroll
    for (int j = 0; j < D_LAT; ++j) acc[j] = fmaxf(acc[j], 0.f);

    // stage 2
    float acc2[D_LAT];
    #pragma unroll
    for (int j = 0; j < D_LAT; ++j) acc2[j] = B1b_l[j];
    #pragma unroll 1
    for (int c = 0; c < D_LAT / 8; ++c) {
        #pragma unroll
        for (int kk = 0; kk < 8; ++kk) {
            const float h = acc[c * 8 + kk];
            const float* wr = W1b_l + (c * 8 + kk) * D_LAT;           // uniform
            #pragma unroll
            for (int j = 0; j < D_LAT; ++j)
                acc2[j] = fmaf(h, wr[j], acc2[j]);
        }
    }

    float4* eo = (float4*)(out + n * D_LAT);
    float4* oo = (float4*)(outb + n * D_LAT);
    #pragma unroll
    for (int q = 0; q < D_LAT / 4; ++q) {
        const float4 prev = oo[q];
        eo[q] = make_float4(acc2[q*4], acc2[q*4+1], acc2[q*4+2], acc2[q*4+3]);
        oo[q] = make_float4(fmaf(al, acc2[q*4], prev.x),
                            fmaf(al, acc2[q*4+1], prev.y),
                            fmaf(al, acc2[q*4+2], prev.z),
                            fmaf(al, acc2[q*4+3], prev.w));
    }
}

// ---------------------------------------------------------------------------
// Per-graph top-30 (stable ties -> smaller index) + gather + relu (unchanged)
// ---------------------------------------------------------------------------
__global__ __launch_bounds__(256) void k_topk(
    const float* __restrict__ ego, const float* __restrict__ outb,
    float* __restrict__ y)
{
    __shared__ float vals[512];
    __shared__ int topidx[K_TOP];
    __shared__ float wv[4];
    __shared__ int wi[4];

    const int g = blockIdx.x, t = threadIdx.x;
    for (int i = t; i < 512; i += 256)
        vals[i] = (i < NPG) ? ego[((size_t)g * NPG + i) * D_LAT + (D_LAT - 1)]
                            : -INFINITY;
    __syncthreads();

    for (int k = 0; k < K_TOP; ++k) {
        float v = -INFINITY; int bi = 0x7fffffff;
        for (int i = t; i < NPG; i += 256) {
            const float x = vals[i];
            if (x > v || (x == v && i < bi)) { v = x; bi = i; }
        }
        for (int off = 32; off > 0; off >>= 1) {
            const float ov = __shfl_down(v, off);
            const int   oi = __shfl_down(bi, off);
            if (ov > v || (ov == v && oi < bi)) { v = ov; bi = oi; }
        }
        if ((t & 63) == 0) { wv[t >> 6] = v; wi[t >> 6] = bi; }
        __syncthreads();
        if (t == 0) {
            for (int w = 1; w < 4; ++w)
                if (wv[w] > v || (wv[w] == v && wi[w] < bi)) { v = wv[w]; bi = wi[w]; }
            topidx[k] = bi;
            vals[bi] = -INFINITY;
        }
        __syncthreads();
    }

    for (int j = t; j < K_TOP * D_LAT; j += 256) {
        const int kk = j >> 5, d = j & 31;
        const size_t node = (size_t)g * NPG + topidx[kk];
        y[(size_t)g * (K_TOP * D_LAT) + j] = fmaxf(outb[node * D_LAT + d], 0.f);
    }
}

// ---------------------------------------------------------------------------
extern "C" void kernel_launch(void* const* d_in, const int* in_sizes, int n_in,
                              void* d_out, int out_size, void* d_ws, size_t ws_size,
                              hipStream_t stream)
{
    const float* X    = (const float*)d_in[0];
    const float* alpha= (const float*)d_in[1];
    const float* w0a  = (const float*)d_in[2];
    const float* b0a  = (const float*)d_in[3];
    const float* w0b  = (const float*)d_in[4];
    const float* b0b  = (const float*)d_in[5];
    const float* W1a  = (const float*)d_in[6];
    const float* B1a  = (const float*)d_in[7];
    const float* W1b  = (const float*)d_in[8];
    const float* B1b  = (const float*)d_in[9];
    const int* esrc   = (const int*)d_in[10];
    const int* edst   = (const int*)d_in[11];
    float* y = (float*)d_out;

    float* egoA   = (float*)d_ws;
    float* outb   = egoA + (size_t)N_NODES * D_LAT;
    float* egoB   = outb + (size_t)N_NODES * D_LAT;
    int*   packed = (int*)egoB;                              // alias: dead before layer 0
    int*   off    = (int*)(egoB + (size_t)N_NODES * D_LAT);  // N+1
    int*   srcidx = off + (N_NODES + 1);                     // E
    int*   ghist  = srcidx + E_EDGES;                        // NB
    int*   gbase  = ghist + NB;                              // NB+1
    int*   gcursor= gbase + (NB + 1);                        // NB
    float* wfold  = (float*)(gcursor + NB);                  // 3 * 2048

    k_foldw<<<L_LAYERS, 256, 0, stream>>>(W1a, wfold);

    hipMemsetAsync(ghist, 0, NB * sizeof(int), stream);
    k_bcount  <<<CBLOCKS, 256, 0, stream>>>(edst, ghist);
    k_bscan   <<<1, 1024, 0, stream>>>(ghist, gbase, gcursor);
    k_bscatter<<<CBLOCKS, 256, 0, stream>>>(esrc, edst, gcursor, packed);
    k_bcsr    <<<NB, 256, 0, stream>>>(gbase, packed, off, srcidx);

    k_mlp0<<<N_NODES / 256, 256, 0, stream>>>(X, w0a, b0a, w0b, b0b, alpha, egoA, outb);

    float* cur = egoA;
    float* nxt = egoB;
    for (int l = 0; l < L_LAYERS; ++l) {
        k_layer<<<N_NODES / 256, 256, 0, stream>>>(
            cur, off, srcidx, wfold + (size_t)l * 2 * D_LAT * D_LAT,
            W1b + (size_t)l * D_LAT * D_LAT, B1a + (size_t)l * D_LAT,
            B1b + (size_t)l * D_LAT, alpha, l, nxt, outb);
        float* tmp = cur; cur = nxt; nxt = tmp;
    }

    // after 3 layers, final ego is in `cur` (== egoB)
    k_topk<<<B_G, 256, 0, stream>>>(cur, outb, y);
}